// Round 1
// baseline (1514.568 us; speedup 1.0000x reference)
//
#include <hip/hip_runtime.h>
#include <hip/hip_bf16.h>

#define B_SZ      512
#define INPUT_DIM 1536
#define MAMBA_DIM 1024
#define OUT_DIM   1024
#define D_STATE   128
#define HEADDIM   64
#define D_INNER   2048
#define NHEADS    32
#define CONV_DIM  2304
#define D_IN_PROJ 4384   // 2*2048 + 2*128 + 32

__device__ __forceinline__ float silu_f(float x) {
    return x / (1.0f + __expf(-x) * 0.0f + expf(-x) * 1.0f); // keep precise expf
}
__device__ __forceinline__ float silu_precise(float x) {
    return x / (1.0f + expf(-x));
}

// ---------------------------------------------------------------------------
// SGEMM: C[M,N] = A[M,K] @ W[K,N] (+ bias[N] if bias != nullptr)
// Tile 64x64, BK=32, 256 threads, 4x4 microtile. M % 64 == 0, K % 32 == 0,
// N % 4 == 0 (bounds-checked on N).
// ---------------------------------------------------------------------------
__global__ __launch_bounds__(256) void sgemm_kernel(
    const float* __restrict__ A, const float* __restrict__ W,
    const float* __restrict__ bias, float* __restrict__ C,
    int M, int N, int K)
{
    __shared__ float As[32][64];      // [k][m]
    __shared__ float Bs[32][64];      // [k][n]

    const int t   = threadIdx.x;
    const int bn0 = blockIdx.x * 64;
    const int bm0 = blockIdx.y * 64;
    const int tr  = t >> 4;           // 0..15
    const int tc  = t & 15;           // 0..15

    float acc[4][4] = {};

    for (int k0 = 0; k0 < K; k0 += 32) {
        // A tile: 64 rows x 32 k = 512 float4 loads (2 per thread)
        #pragma unroll
        for (int i = 0; i < 2; ++i) {
            int idx = t + i * 256;
            int row = idx >> 3;
            int c4  = (idx & 7) * 4;
            float4 v = *(const float4*)(A + (size_t)(bm0 + row) * K + k0 + c4);
            As[c4 + 0][row] = v.x;
            As[c4 + 1][row] = v.y;
            As[c4 + 2][row] = v.z;
            As[c4 + 3][row] = v.w;
        }
        // B tile: 32 k x 64 n = 512 float4 loads (2 per thread)
        #pragma unroll
        for (int i = 0; i < 2; ++i) {
            int idx = t + i * 256;
            int kr  = idx >> 4;
            int c4  = (idx & 15) * 4;
            int n   = bn0 + c4;
            float4 v = make_float4(0.f, 0.f, 0.f, 0.f);
            if (n < N) v = *(const float4*)(W + (size_t)(k0 + kr) * N + n);
            *(float4*)&Bs[kr][c4] = v;
        }
        __syncthreads();

        #pragma unroll
        for (int k = 0; k < 32; ++k) {
            float4 a = *(const float4*)&As[k][tr * 4];
            float4 b = *(const float4*)&Bs[k][tc * 4];
            float av[4] = {a.x, a.y, a.z, a.w};
            float bv[4] = {b.x, b.y, b.z, b.w};
            #pragma unroll
            for (int i = 0; i < 4; ++i)
                #pragma unroll
                for (int j = 0; j < 4; ++j)
                    acc[i][j] += av[i] * bv[j];
        }
        __syncthreads();
    }

    #pragma unroll
    for (int i = 0; i < 4; ++i) {
        int m = bm0 + tr * 4 + i;
        #pragma unroll
        for (int j = 0; j < 4; ++j) {
            int n = bn0 + tc * 4 + j;
            if (n < N) {
                float v = acc[i][j];
                if (bias) v += bias[n];
                C[(size_t)m * N + n] = v;
            }
        }
    }
}

// ---------------------------------------------------------------------------
// RMSNorm over 1024 cols (+ optional SiLU). One block (256 thr) per row.
// ---------------------------------------------------------------------------
template <bool SILU>
__global__ __launch_bounds__(256) void rmsnorm_kernel(
    const float* __restrict__ X, const float* __restrict__ g,
    float* __restrict__ Y)
{
    const int row = blockIdx.x;
    const float* x = X + (size_t)row * 1024;
    float4 v = *(const float4*)(x + threadIdx.x * 4);
    float ss = v.x * v.x + v.y * v.y + v.z * v.z + v.w * v.w;
    #pragma unroll
    for (int off = 32; off > 0; off >>= 1) ss += __shfl_down(ss, off);

    __shared__ float wsum[4];
    const int wid = threadIdx.x >> 6;
    if ((threadIdx.x & 63) == 0) wsum[wid] = ss;
    __syncthreads();
    const float tot = wsum[0] + wsum[1] + wsum[2] + wsum[3];
    const float rs = 1.0f / sqrtf(tot * (1.0f / 1024.0f) + 1e-5f);

    float4 gv = *(const float4*)(g + threadIdx.x * 4);
    float4 o;
    o.x = v.x * rs * gv.x;
    o.y = v.y * rs * gv.y;
    o.z = v.z * rs * gv.z;
    o.w = v.w * rs * gv.w;
    if (SILU) {
        o.x = silu_precise(o.x);
        o.y = silu_precise(o.y);
        o.z = silu_precise(o.z);
        o.w = silu_precise(o.w);
    }
    *(float4*)(Y + (size_t)row * 1024 + threadIdx.x * 4) = o;
}

// ---------------------------------------------------------------------------
// Conv state shift + depthwise conv + SiLU. One thread per (b, c).
// Writes conv_state_new (output 1) and xbc_conv (ws).
// ---------------------------------------------------------------------------
__global__ __launch_bounds__(256) void conv_kernel(
    const float* __restrict__ conv_state, const float* __restrict__ zx,
    const float* __restrict__ conv_w, const float* __restrict__ conv_b,
    float* __restrict__ conv_state_out, float* __restrict__ xbc_out)
{
    const int gid = blockIdx.x * 256 + threadIdx.x;  // b*CONV_DIM + c
    const int b = gid / CONV_DIM;
    const int c = gid - b * CONV_DIM;

    float4 cs = *(const float4*)(conv_state + (size_t)gid * 4);
    float xn = zx[(size_t)b * D_IN_PROJ + D_INNER + c];
    float4 w = *(const float4*)(conv_w + c * 4);

    float s = cs.y * w.x + cs.z * w.y + cs.w * w.z + xn * w.w + conv_b[c];
    float r = silu_precise(s);

    float4 o = make_float4(cs.y, cs.z, cs.w, xn);
    *(float4*)(conv_state_out + (size_t)gid * 4) = o;
    xbc_out[gid] = r;
}

// ---------------------------------------------------------------------------
// SSM state update + y. Block = (head h, batch b), 256 threads.
// Thread t: p = t/4, n-chunk = (t%4)*32 .. +31 (8 float4 = 128B contiguous).
// ---------------------------------------------------------------------------
__global__ __launch_bounds__(256) void ssm_kernel(
    const float* __restrict__ ssm_state, const float* __restrict__ xbc,
    const float* __restrict__ zx, const float* __restrict__ A_log,
    const float* __restrict__ dt_bias, const float* __restrict__ Dp,
    float* __restrict__ ssm_out, float* __restrict__ yz)
{
    const int h = blockIdx.x;   // 0..31
    const int b = blockIdx.y;   // 0..511
    const int t = threadIdx.x;
    const int p = t >> 2;            // 0..63
    const int nc = (t & 3) * 32;     // n base

    float dtv = zx[(size_t)b * D_IN_PROJ + (D_INNER + CONV_DIM) + h] + dt_bias[h];
    dtv = (dtv > 20.f) ? dtv : log1pf(expf(dtv));
    const float a  = -expf(A_log[h]);
    const float da = expf(dtv * a);

    const float* xrow = xbc + (size_t)b * CONV_DIM;
    const float xh = xrow[h * HEADDIM + p];
    const float coef = dtv * xh;

    const size_t base = (((size_t)b * NHEADS + h) * HEADDIM + p) * D_STATE + nc;
    const float* sp = ssm_state + base;
    float* so = ssm_out + base;
    const float* bv = xrow + D_INNER + nc;
    const float* cv = xrow + D_INNER + D_STATE + nc;

    float y = 0.f;
    #pragma unroll
    for (int i = 0; i < 8; ++i) {
        float4 s  = *(const float4*)(sp + i * 4);
        float4 bb = *(const float4*)(bv + i * 4);
        float4 cc = *(const float4*)(cv + i * 4);
        float4 ns;
        ns.x = s.x * da + coef * bb.x;
        ns.y = s.y * da + coef * bb.y;
        ns.z = s.z * da + coef * bb.z;
        ns.w = s.w * da + coef * bb.w;
        y += ns.x * cc.x + ns.y * cc.y + ns.z * cc.z + ns.w * cc.w;
        *(float4*)(so + i * 4) = ns;
    }
    y += __shfl_xor(y, 1);
    y += __shfl_xor(y, 2);
    if ((t & 3) == 0) {
        float z = zx[(size_t)b * D_IN_PROJ + h * HEADDIM + p];
        float yv = y + Dp[h] * xh;
        yz[(size_t)b * D_INNER + h * HEADDIM + p] = yv * silu_precise(z);
    }
}

// ---------------------------------------------------------------------------

extern "C" void kernel_launch(void* const* d_in, const int* in_sizes, int n_in,
                              void* d_out, int out_size, void* d_ws, size_t ws_size,
                              hipStream_t stream)
{
    const float* x          = (const float*)d_in[0];   // 512 x 1536
    const float* conv_state = (const float*)d_in[1];   // 512 x 2304 x 4
    const float* ssm_state  = (const float*)d_in[2];   // 512 x 32 x 64 x 128
    const float* w_in       = (const float*)d_in[3];   // 1536 x 1024
    const float* b_in       = (const float*)d_in[4];   // 1024
    const float* g_in       = (const float*)d_in[5];   // 1024
    const float* W_inproj   = (const float*)d_in[6];   // 1024 x 4384
    const float* conv_w     = (const float*)d_in[7];   // 2304 x 4
    const float* conv_b     = (const float*)d_in[8];   // 2304
    const float* A_log      = (const float*)d_in[9];   // 32
    const float* dt_bias    = (const float*)d_in[10];  // 32
    const float* Dp         = (const float*)d_in[11];  // 32
    const float* W_mamba_out= (const float*)d_in[12];  // 2048 x 1024
    const float* w_out      = (const float*)d_in[13];  // 1024 x 1024
    const float* b_out      = (const float*)d_in[14];  // 1024
    const float* g_outnorm  = (const float*)d_in[15];  // 1024

    float* out_y    = (float*)d_out;                                   // 512*1024
    float* out_conv = out_y + (size_t)B_SZ * OUT_DIM;                  // 512*2304*4
    float* out_ssm  = out_conv + (size_t)B_SZ * CONV_DIM * 4;          // 512*32*64*128

    float* ws  = (float*)d_ws;
    float* t1  = ws;                                  // 512*1024 (gemm1 out)
    float* h   = t1  + (size_t)B_SZ * MAMBA_DIM;      // 512*1024
    float* zx  = h   + (size_t)B_SZ * MAMBA_DIM;      // 512*4384
    float* xbc = zx  + (size_t)B_SZ * D_IN_PROJ;      // 512*2304
    float* yzb = xbc + (size_t)B_SZ * CONV_DIM;       // 512*2048
    float* u   = yzb + (size_t)B_SZ * D_INNER;        // 512*1024
    float* t2  = u   + (size_t)B_SZ * MAMBA_DIM;      // 512*1024

    // 1) t1 = x @ w_in + b_in
    sgemm_kernel<<<dim3(MAMBA_DIM / 64, B_SZ / 64), 256, 0, stream>>>(
        x, w_in, b_in, t1, B_SZ, MAMBA_DIM, INPUT_DIM);
    // 2) h = silu(rmsnorm(t1, g_in))
    rmsnorm_kernel<true><<<B_SZ, 256, 0, stream>>>(t1, g_in, h);
    // 3) zx = h @ W_inproj
    sgemm_kernel<<<dim3((D_IN_PROJ + 63) / 64, B_SZ / 64), 256, 0, stream>>>(
        h, W_inproj, nullptr, zx, B_SZ, D_IN_PROJ, MAMBA_DIM);
    // 4) conv state shift + conv + silu
    conv_kernel<<<(B_SZ * CONV_DIM) / 256, 256, 0, stream>>>(
        conv_state, zx, conv_w, conv_b, out_conv, xbc);
    // 5) ssm update + gated y
    ssm_kernel<<<dim3(NHEADS, B_SZ), 256, 0, stream>>>(
        ssm_state, xbc, zx, A_log, dt_bias, Dp, out_ssm, yzb);
    // 6) u = yz @ W_mamba_out
    sgemm_kernel<<<dim3(MAMBA_DIM / 64, B_SZ / 64), 256, 0, stream>>>(
        yzb, W_mamba_out, nullptr, u, B_SZ, MAMBA_DIM, D_INNER);
    // 7) t2 = u @ w_out + b_out
    sgemm_kernel<<<dim3(OUT_DIM / 64, B_SZ / 64), 256, 0, stream>>>(
        u, w_out, b_out, t2, B_SZ, OUT_DIM, MAMBA_DIM);
    // 8) out_y = rmsnorm(t2, g_outnorm)
    rmsnorm_kernel<false><<<B_SZ, 256, 0, stream>>>(t2, g_outnorm, out_y);
}